// Round 1
// baseline (5721.078 us; speedup 1.0000x reference)
//
#include <hip/hip_runtime.h>

typedef __bf16 bf16x8 __attribute__((ext_vector_type(8)));
typedef float f32x4 __attribute__((ext_vector_type(4)));
typedef unsigned int uint32;
typedef unsigned short ushort16_t;

#define T_STEPS 1024
#define BATCH 256

// ---------------- LDS layout (byte offsets) ----------------
// A-operand tiles stored row-major [16][Kpad] bf16 with row stride = 2*Kpad+16
#define INP_OFF   0                      // 16 x 32,  stride 80   (cols 0-15 u_t, 16-31 x_prev)
#define INP_STR   80
#define H0_OFF    1280                   // 2 ping-pong buffers 16 x 128, stride 272 (4352 B each)
#define H_STR     272
#define H1_OFF    (H0_OFF + 2*4352)      // 9984
#define DIN_OFF   (H1_OFF + 2*4352)      // 18688: 16 x 160, stride 336 (u | h1n | pad)
#define DM_STR    336
#define MIN_OFF   (DIN_OFF + 16*336)     // 24064: 16 x 160 (x_t | h0n | pad)
#define DTMP_OFF  (MIN_OFF + 16*336)     // 29440: 16 x 128
#define M1_OFF    (DTMP_OFF + 4352)      // 33792
#define M2_OFF    (M1_OFF + 4352)        // 38144
#define LDS_BYTES (M2_OFF + 4352)        // 42496

// ---------------- weight-fragment buffer (in d_ws), uint4 (=8 bf16) base offsets ----------
#define U4_G0 0        // Wih0 384x32   KT=1 NT=24
#define U4_G1 1536     // Whh0 384x128  KT=4 NT=24
#define U4_G2 7680     // Wih1 384x128
#define U4_G3 13824    // Whh1 384x128
#define U4_G4 19968    // dW1 128x144 -> Kpad 160, KT=5 NT=8
#define U4_G5 22528    // dW2 16x128  KT=4 NT=1
#define U4_G6 22784    // mW1 128x144 KT=5 NT=8
#define U4_G7 25344    // mW2 128x128 KT=4 NT=8
#define U4_G8 27392    // mW3 16x128  KT=4 NT=1
#define FRAG_ELEMS 221184   // bf16 elements total (442368 bytes)

static __device__ __forceinline__ ushort16_t f2bf(float f) {
    uint32 u = __builtin_bit_cast(uint32, f);
    return (ushort16_t)((u + 0x7FFFu + ((u >> 16) & 1u)) >> 16);
}
static __device__ __forceinline__ float bf2f(ushort16_t h) {
    uint32 u = ((uint32)h) << 16;
    return __builtin_bit_cast(float, u);
}
static __device__ __forceinline__ float sigm(float x) { return 1.f / (1.f + __expf(-x)); }
static __device__ __forceinline__ float tanh_fast(float x) {
    x = fmaxf(fminf(x, 30.f), -30.f);
    float e = __expf(-2.f * x);
    return (1.f - e) / (1.f + e);
}
static __device__ __forceinline__ f32x4 mfma16(bf16x8 a, bf16x8 b, f32x4 c) {
    return __builtin_amdgcn_mfma_f32_16x16x32_bf16(a, b, c, 0, 0, 0);
}
// A fragment from LDS tile: lane holds A[row=lane&15][kt*32 + (lane>>4)*8 + 0..7]
static __device__ __forceinline__ bf16x8 ldsA(const char* base, int stride, int kt, int lane) {
    const uint4* p = (const uint4*)(base + (lane & 15) * stride + kt * 64 + (lane >> 4) * 16);
    return __builtin_bit_cast(bf16x8, *p);
}
// B fragment from global frag buffer
static __device__ __forceinline__ bf16x8 gfrag(const uint4* F, int u4base, int tile, int lane) {
    return __builtin_bit_cast(bf16x8, F[u4base + tile * 64 + lane]);
}

// ---------------- prep: weights fp32 row-major -> bf16 B-fragment order; also zero d_out ----
__global__ void prep_frags(const float* __restrict__ W0, const float* __restrict__ W1,
                           const float* __restrict__ W2, const float* __restrict__ W3,
                           const float* __restrict__ W4, const float* __restrict__ W5,
                           const float* __restrict__ W6, const float* __restrict__ W7,
                           const float* __restrict__ W8,
                           ushort16_t* __restrict__ frag, float* __restrict__ out) {
    const int b = blockIdx.x;      // 0..431 global tile id
    const int lane = threadIdx.x;  // 0..63
    if (b == 0 && lane == 0) *out = 0.f;

    const int cumT[10] = {0, 24, 120, 216, 312, 352, 356, 396, 428, 432};
    const int Kreal[9] = {32, 128, 128, 128, 144, 128, 144, 128, 128};
    const int KT[9]    = {1, 4, 4, 4, 5, 4, 5, 4, 4};
    const int ebase[9] = {0, 12288, 61440, 110592, 159744, 180224, 182272, 202752, 219136};
    const float* Ws[9] = {W0, W1, W2, W3, W4, W5, W6, W7, W8};

    int g = 0;
    while (b >= cumT[g + 1]) ++g;
    const int tl = b - cumT[g];
    const int kt = tl % KT[g];
    const int n = (tl / KT[g]) * 16 + (lane & 15);
    const float* W = Ws[g];
    ushort16_t* o = frag + ebase[g] + tl * 512 + lane * 8;
#pragma unroll
    for (int j = 0; j < 8; ++j) {
        int k = kt * 32 + (lane >> 4) * 8 + j;
        o[j] = (k < Kreal[g]) ? f2bf(W[n * Kreal[g] + k]) : (ushort16_t)0;
    }
}

// ---------------- main persistent recurrence kernel: 16 WG x 512 thr ----------------
__global__ __launch_bounds__(512) void rnn_main(
    const float* __restrict__ u, const float* __restrict__ yg, const float* __restrict__ h0g,
    const ushort16_t* __restrict__ frag,
    const float* __restrict__ db1g, const float* __restrict__ db2g,
    const float* __restrict__ mb1g, const float* __restrict__ mb2g, const float* __restrict__ mb3g,
    float* __restrict__ out) {
    __shared__ __align__(16) char smem[LDS_BYTES];
    const int tid = threadIdx.x;
    const int lane = tid & 63;
    const int w = tid >> 6;      // wave 0..7: owns cols w*16..w*16+15 of each 128/384-wide output
    const int lr = lane & 15;
    const int lg = lane >> 4;
    const int r0 = blockIdx.x * 16;  // batch rows [r0, r0+16)

    // ---- init: zero inp (x_prev=0), zero K-pads of d_in/m_in, load h0 -> bf16 LDS ----
    for (int i = tid; i < 16 * 32; i += 512) {
        int row = i >> 5, col = i & 31;
        *(ushort16_t*)(smem + INP_OFF + row * INP_STR + col * 2) = 0;
    }
    for (int i = tid; i < 16 * 16; i += 512) {
        int row = i >> 4, col = 144 + (i & 15);
        *(ushort16_t*)(smem + DIN_OFF + row * DM_STR + col * 2) = 0;
        *(ushort16_t*)(smem + MIN_OFF + row * DM_STR + col * 2) = 0;
    }
    for (int i = tid; i < 16 * 128; i += 512) {
        int row = i >> 7, k = i & 127;
        *(ushort16_t*)(smem + H0_OFF + row * H_STR + k * 2) = f2bf(h0g[(0 * BATCH + r0 + row) * 128 + k]);
        *(ushort16_t*)(smem + H1_OFF + row * H_STR + k * 2) = f2bf(h0g[(1 * BATCH + r0 + row) * 128 + k]);
    }
    __syncthreads();

    const float db1_v = db1g[w * 16 + lr];
    const float mb1_v = mb1g[w * 16 + lr];
    const float mb2_v = mb2g[w * 16 + lr];
    const float db2_v = db2g[lr];
    const float mb3_v = mb3g[lr];
    const uint4* F = (const uint4*)frag;
    const f32x4 zero = {0.f, 0.f, 0.f, 0.f};
    float loss = 0.f;
    const int c = w * 16 + lr;  // this wave+lane's output column

    for (int t = 0; t < T_STEPS; ++t) {
        const int cur = t & 1, nxt = cur ^ 1;
        char* h0c = smem + H0_OFF + cur * 4352;
        char* h0n = smem + H0_OFF + nxt * 4352;
        char* h1c = smem + H1_OFF + cur * 4352;
        char* h1n = smem + H1_OFF + nxt * 4352;

        // stage u_t into inp[:,0:16] and d_in[:,0:16] (wave 0)
        if (w == 0) {
            int row = lane >> 2, jb = (lane & 3) * 4;
#pragma unroll
            for (int jj = 0; jj < 4; ++jj) {
                ushort16_t b = f2bf(u[((r0 + row) * 16 + jb + jj) * 1024 + t]);
                *(ushort16_t*)(smem + INP_OFF + row * INP_STR + (jb + jj) * 2) = b;
                *(ushort16_t*)(smem + DIN_OFF + row * DM_STR + (jb + jj) * 2) = b;
            }
        }
        __syncthreads();

        // ---- Phase A: GRU layer 0. gi = [u|x] @ Wih0^T, gh = h0 @ Whh0^T ----
        {
            bf16x8 a_inp = ldsA(smem + INP_OFF, INP_STR, 0, lane);
            bf16x8 ah[4];
#pragma unroll
            for (int kt = 0; kt < 4; ++kt) ah[kt] = ldsA(h0c, H_STR, kt, lane);
            f32x4 ar = mfma16(a_inp, gfrag(F, U4_G0, w, lane), zero);
            f32x4 az = mfma16(a_inp, gfrag(F, U4_G0, 8 + w, lane), zero);
            f32x4 ain = mfma16(a_inp, gfrag(F, U4_G0, 16 + w, lane), zero);
            f32x4 ahn = zero;
#pragma unroll
            for (int kt = 0; kt < 4; ++kt) {
                ar = mfma16(ah[kt], gfrag(F, U4_G1, w * 4 + kt, lane), ar);
                az = mfma16(ah[kt], gfrag(F, U4_G1, (8 + w) * 4 + kt, lane), az);
                ahn = mfma16(ah[kt], gfrag(F, U4_G1, (16 + w) * 4 + kt, lane), ahn);
            }
#pragma unroll
            for (int i = 0; i < 4; ++i) {
                int row = lg * 4 + i;  // D layout: col=lane&15, row=(lane>>4)*4+i
                float hold = bf2f(*(const ushort16_t*)(h0c + row * H_STR + c * 2));
                float r = sigm(ar[i]);
                float z = sigm(az[i]);
                float n = tanh_fast(ain[i] + r * ahn[i]);
                ushort16_t hb = f2bf((1.f - z) * n + z * hold);
                *(ushort16_t*)(h0n + row * H_STR + c * 2) = hb;
                *(ushort16_t*)(smem + MIN_OFF + row * DM_STR + (16 + c) * 2) = hb;  // m_in h0n part
            }
        }
        __syncthreads();

        // ---- Phase B: GRU layer 1. gi = h0n @ Wih1^T, gh = h1 @ Whh1^T ----
        {
            bf16x8 ag[4], ah[4];
#pragma unroll
            for (int kt = 0; kt < 4; ++kt) {
                ag[kt] = ldsA(h0n, H_STR, kt, lane);
                ah[kt] = ldsA(h1c, H_STR, kt, lane);
            }
            f32x4 ar = zero, az = zero, ain = zero, ahn = zero;
#pragma unroll
            for (int kt = 0; kt < 4; ++kt) {
                ar = mfma16(ag[kt], gfrag(F, U4_G2, w * 4 + kt, lane), ar);
                az = mfma16(ag[kt], gfrag(F, U4_G2, (8 + w) * 4 + kt, lane), az);
                ain = mfma16(ag[kt], gfrag(F, U4_G2, (16 + w) * 4 + kt, lane), ain);
                ar = mfma16(ah[kt], gfrag(F, U4_G3, w * 4 + kt, lane), ar);
                az = mfma16(ah[kt], gfrag(F, U4_G3, (8 + w) * 4 + kt, lane), az);
                ahn = mfma16(ah[kt], gfrag(F, U4_G3, (16 + w) * 4 + kt, lane), ahn);
            }
#pragma unroll
            for (int i = 0; i < 4; ++i) {
                int row = lg * 4 + i;
                float hold = bf2f(*(const ushort16_t*)(h1c + row * H_STR + c * 2));
                float r = sigm(ar[i]);
                float z = sigm(az[i]);
                float n = tanh_fast(ain[i] + r * ahn[i]);
                ushort16_t hb = f2bf((1.f - z) * n + z * hold);
                *(ushort16_t*)(h1n + row * H_STR + c * 2) = hb;
                *(ushort16_t*)(smem + DIN_OFF + row * DM_STR + (16 + c) * 2) = hb;  // d_in h1n part
            }
        }
        __syncthreads();

        // ---- Phase C1: d_tmp = d_in @ dW1^T + db1 ----
        {
            f32x4 acc = zero;
#pragma unroll
            for (int kt = 0; kt < 5; ++kt)
                acc = mfma16(ldsA(smem + DIN_OFF, DM_STR, kt, lane), gfrag(F, U4_G4, w * 5 + kt, lane), acc);
#pragma unroll
            for (int i = 0; i < 4; ++i) {
                int row = lg * 4 + i;
                *(ushort16_t*)(smem + DTMP_OFF + row * H_STR + c * 2) = f2bf(acc[i] + db1_v);
            }
        }
        __syncthreads();

        // ---- Phase C2 (wave 0): x_t = d_tmp @ dW2^T + db2 -> inp[:,16:32], m_in[:,0:16] ----
        if (w == 0) {
            f32x4 acc = zero;
#pragma unroll
            for (int kt = 0; kt < 4; ++kt)
                acc = mfma16(ldsA(smem + DTMP_OFF, H_STR, kt, lane), gfrag(F, U4_G5, kt, lane), acc);
#pragma unroll
            for (int i = 0; i < 4; ++i) {
                int row = lg * 4 + i;
                ushort16_t xb = f2bf(acc[i] + db2_v);
                *(ushort16_t*)(smem + INP_OFF + row * INP_STR + (16 + lr) * 2) = xb;
                *(ushort16_t*)(smem + MIN_OFF + row * DM_STR + lr * 2) = xb;
            }
        }
        __syncthreads();

        // ---- Phase D1: m1 = relu(m_in @ mW1^T + mb1) ----
        {
            f32x4 acc = zero;
#pragma unroll
            for (int kt = 0; kt < 5; ++kt)
                acc = mfma16(ldsA(smem + MIN_OFF, DM_STR, kt, lane), gfrag(F, U4_G6, w * 5 + kt, lane), acc);
#pragma unroll
            for (int i = 0; i < 4; ++i) {
                int row = lg * 4 + i;
                *(ushort16_t*)(smem + M1_OFF + row * H_STR + c * 2) = f2bf(fmaxf(acc[i] + mb1_v, 0.f));
            }
        }
        __syncthreads();

        // ---- Phase D2: m2 = m1 @ mW2^T + mb2 ----
        {
            f32x4 acc = zero;
#pragma unroll
            for (int kt = 0; kt < 4; ++kt)
                acc = mfma16(ldsA(smem + M1_OFF, H_STR, kt, lane), gfrag(F, U4_G7, w * 4 + kt, lane), acc);
#pragma unroll
            for (int i = 0; i < 4; ++i) {
                int row = lg * 4 + i;
                *(ushort16_t*)(smem + M2_OFF + row * H_STR + c * 2) = f2bf(acc[i] + mb2_v);
            }
        }
        __syncthreads();

        // ---- Phase D3 (wave 1): y_hat = m2 @ mW3^T + mb3; loss += (y_hat - y_t)^2 ----
        if (w == 1) {
            f32x4 acc = zero;
#pragma unroll
            for (int kt = 0; kt < 4; ++kt)
                acc = mfma16(ldsA(smem + M2_OFF, H_STR, kt, lane), gfrag(F, U4_G8, kt, lane), acc);
#pragma unroll
            for (int i = 0; i < 4; ++i) {
                int row = lg * 4 + i;
                float yh = acc[i] + mb3_v;
                float yv = yg[((r0 + row) * 16 + lr) * 1024 + t];
                float d = yh - yv;
                loss += d * d;
            }
        }
        // no barrier needed: next-iter stage barrier orders everything
    }

    if (w == 1) {
#pragma unroll
        for (int off = 32; off > 0; off >>= 1) loss += __shfl_down(loss, off, 64);
        if (lane == 0) atomicAdd(out, loss);
    }
}

extern "C" void kernel_launch(void* const* d_in, const int* in_sizes, int n_in,
                              void* d_out, int out_size, void* d_ws, size_t ws_size,
                              hipStream_t stream) {
    const float* u    = (const float*)d_in[0];
    const float* y    = (const float*)d_in[1];
    const float* h0   = (const float*)d_in[2];
    const float* Wih0 = (const float*)d_in[3];
    const float* Whh0 = (const float*)d_in[4];
    const float* Wih1 = (const float*)d_in[5];
    const float* Whh1 = (const float*)d_in[6];
    const float* dW1  = (const float*)d_in[7];
    const float* db1  = (const float*)d_in[8];
    const float* dW2  = (const float*)d_in[9];
    const float* db2  = (const float*)d_in[10];
    const float* mW1  = (const float*)d_in[11];
    const float* mb1  = (const float*)d_in[12];
    const float* mW2  = (const float*)d_in[13];
    const float* mb2  = (const float*)d_in[14];
    const float* mW3  = (const float*)d_in[15];
    const float* mb3  = (const float*)d_in[16];
    float* out = (float*)d_out;
    ushort16_t* frag = (ushort16_t*)d_ws;

    prep_frags<<<dim3(432), dim3(64), 0, stream>>>(Wih0, Whh0, Wih1, Whh1, dW1, dW2, mW1, mW2, mW3,
                                                   frag, out);
    rnn_main<<<dim3(16), dim3(512), 0, stream>>>(u, y, h0, frag, db1, db2, mb1, mb2, mb3, out);
}

// Round 2
// 4440.301 us; speedup vs baseline: 1.2884x; 1.2884x over previous
//
#include <hip/hip_runtime.h>

typedef __bf16 bf16x8 __attribute__((ext_vector_type(8)));
typedef float f32x4 __attribute__((ext_vector_type(4)));
typedef unsigned int uint32;
typedef unsigned short ushort16_t;

#define T_STEPS 1024
#define CHUNK 32

// ---------------- LDS layout (byte offsets), all 16B aligned ----------------
#define H0_OFF   0              // 2 ping-pong [16][272B] (16 rows x 128 bf16 + 16B pad)
#define H1_OFF   8704
#define M1_OFF   17408          // [16][272B]
#define XB_OFF   21760          // [16][48B]  (16 rows x 16 bf16, stride 48)
#define ZP_OFF   22528          // 64B zero block
#define UCH_OFF  22592          // [32 s][16 r][48B]  u chunk (bf16)
#define YCH_OFF  47168          // [32 s][16 r][48B]  y chunk (bf16)
#define WL_OFF   71744          // 73 weight tiles x 1024B (G0:0..23, G4:24..28, G5:29..68, G6:69..72)
#define LDS_BYTES 146496

// ---------------- global frag buffer: tile bases (tile = 512 bf16 = 1KB) ----
#define TG0 0     // Wih0 [384,32]   KT=1 NT=24
#define TG1 24    // Whh0 [384,128]  KT=4 NT=24
#define TG2 120   // Wih1 [384,128]
#define TG3 216   // Whh1 [384,128]
#define TG4 312   // dC   [16,144->160] KT=5 NT=1
#define TG5 317   // mW1  [128,144->160] KT=5 NT=8
#define TG6 357   // mE   [16,128]   KT=4 NT=1
#define NT_TOT 361
// fp32 scratch (byte offsets in d_ws)
#define SC_DC  369664   // dC fp32 [16][144]
#define SC_ME  378880   // mE fp32 [16][128]
#define SC_DBC 387072   // dbC fp32 [16]
#define SC_MBE 387136   // mbE fp32 [16]

static __device__ __forceinline__ ushort16_t f2bf(float f) {
    uint32 u = __builtin_bit_cast(uint32, f);
    return (ushort16_t)((u + 0x7FFFu + ((u >> 16) & 1u)) >> 16);
}
static __device__ __forceinline__ float bf2f(ushort16_t h) {
    uint32 u = ((uint32)h) << 16;
    return __builtin_bit_cast(float, u);
}
static __device__ __forceinline__ float sigm(float x) { return 1.f / (1.f + __expf(-x)); }
static __device__ __forceinline__ float tanh_fast(float x) {
    x = fmaxf(fminf(x, 30.f), -30.f);
    float e = __expf(-2.f * x);
    return (1.f - e) / (1.f + e);
}
static __device__ __forceinline__ f32x4 mfma16(bf16x8 a, bf16x8 b, f32x4 c) {
    return __builtin_amdgcn_mfma_f32_16x16x32_bf16(a, b, c, 0, 0, 0);
}
static __device__ __forceinline__ bf16x8 ldsAF(const char* p) {
    return __builtin_bit_cast(bf16x8, *(const uint4*)p);
}

// ---------------- prep1: combined matrices + biases (fp32), zero d_out ----------------
__global__ void prep1(const float* __restrict__ dW1, const float* __restrict__ db1,
                      const float* __restrict__ dW2, const float* __restrict__ db2,
                      const float* __restrict__ mW2, const float* __restrict__ mb2,
                      const float* __restrict__ mW3, const float* __restrict__ mb3,
                      char* __restrict__ ws, float* __restrict__ out) {
    int id = blockIdx.x * 256 + threadIdx.x;
    if (id == 0) *out = 0.f;
    if (id < 2304) {                       // dC[n][k] = sum_h dW2[n][h]*dW1[h][k]
        int n = id / 144, k = id % 144;
        float s = 0.f;
        for (int h = 0; h < 128; ++h) s += dW2[n * 128 + h] * dW1[h * 144 + k];
        ((float*)(ws + SC_DC))[id] = s;
    } else if (id < 4352) {                // mE[n][k] = sum_h mW3[n][h]*mW2[h][k]
        int e = id - 2304, n = e / 128, k = e % 128;
        float s = 0.f;
        for (int h = 0; h < 128; ++h) s += mW3[n * 128 + h] * mW2[h * 128 + k];
        ((float*)(ws + SC_ME))[e] = s;
    } else if (id < 4368) {                // dbC = dW2@db1 + db2
        int n = id - 4352;
        float s = db2[n];
        for (int h = 0; h < 128; ++h) s += dW2[n * 128 + h] * db1[h];
        ((float*)(ws + SC_DBC))[n] = s;
    } else if (id < 4384) {                // mbE = mW3@mb2 + mb3
        int n = id - 4368;
        float s = mb3[n];
        for (int h = 0; h < 128; ++h) s += mW3[n * 128 + h] * mb2[h];
        ((float*)(ws + SC_MBE))[n] = s;
    }
}

// ---------------- prep2: pack all weights into MFMA B-fragment order (bf16) ----------------
__global__ void prep2(const float* __restrict__ W0, const float* __restrict__ W1,
                      const float* __restrict__ W2, const float* __restrict__ W3,
                      const float* __restrict__ W5, char* __restrict__ ws) {
    const int tt = blockIdx.x;     // 0..360
    const int lane = threadIdx.x;  // 0..63
    const int cum[8] = {TG0, TG1, TG2, TG3, TG4, TG5, TG6, NT_TOT};
    const int Kreal[7] = {32, 128, 128, 128, 144, 144, 128};
    const int KT[7] = {1, 4, 4, 4, 5, 5, 4};
    const float* Ws[7] = {W0, W1, W2, W3, (const float*)(ws + SC_DC), W5, (const float*)(ws + SC_ME)};
    int g = 0;
    while (tt >= cum[g + 1]) ++g;
    const int tl = tt - cum[g];
    const int kt = tl % KT[g];
    const int n = (tl / KT[g]) * 16 + (lane & 15);
    const float* W = Ws[g];
    ushort16_t* o = (ushort16_t*)ws + tt * 512 + lane * 8;
#pragma unroll
    for (int j = 0; j < 8; ++j) {
        int k = kt * 32 + (lane >> 4) * 8 + j;
        o[j] = (k < Kreal[g]) ? f2bf(W[n * Kreal[g] + k]) : (ushort16_t)0;
    }
}

// ---------------- main: 16 WG x 256 thr (4 waves, 1 wave/SIMD, 512-VGPR budget) ----------
__global__ __launch_bounds__(256, 1) void rnn_main(
    const float* __restrict__ u, const float* __restrict__ yg, const float* __restrict__ h0g,
    const char* __restrict__ ws, const float* __restrict__ mb1g,
    const float* __restrict__ dbCg, const float* __restrict__ mbEg,
    float* __restrict__ out) {
    __shared__ __align__(16) char smem[LDS_BYTES];
    const int tid = threadIdx.x;
    const int lane = tid & 63;
    const int w = tid >> 6;       // wave 0..3: owns cols [w*32, w*32+32)
    const int lr = lane & 15;
    const int lg = lane >> 4;
    const int r0 = blockIdx.x * 16;
    const uint4* F4 = (const uint4*)ws;
    const f32x4 zero = {0.f, 0.f, 0.f, 0.f};

    // ---- init: zero xbuf+zeroblock, load h0 -> LDS bf16, copy LDS-resident weights ----
    for (int i = tid; i < (768 + 64) / 4; i += 256) *(uint32*)(smem + XB_OFF + i * 4) = 0;
    for (int i = tid; i < 1024; i += 256) {  // 2 layers x 16 rows x 32 float4
        int lay = i >> 9, rem = i & 511, rr = rem >> 5, k4 = rem & 31;
        float4 v = *(const float4*)(h0g + (lay * 256 + r0 + rr) * 128 + k4 * 4);
        uint2 pk;
        pk.x = (uint32)f2bf(v.x) | ((uint32)f2bf(v.y) << 16);
        pk.y = (uint32)f2bf(v.z) | ((uint32)f2bf(v.w) << 16);
        *(uint2*)(smem + H0_OFF + lay * 8704 + rr * 272 + k4 * 8) = pk;
    }
    for (int i = tid; i < 73 * 64; i += 256) {  // G0,G4,G5,G6 -> LDS
        int li = i >> 6, ln2 = i & 63;
        int gt2 = (li < 24) ? li : (li < 29) ? TG4 + (li - 24) : (li < 69) ? TG5 + (li - 29) : TG6 + (li - 69);
        *((uint4*)(smem + WL_OFF) + i) = F4[gt2 * 64 + ln2];
    }
    // ---- per-wave register-resident weights: Whh0 / Wih1 / Whh1 (72 tiles = 288 VGPR) ----
    bf16x8 wA[3][2][4], wBi[3][2][4], wBh[3][2][4];
#pragma unroll
    for (int g = 0; g < 3; ++g)
#pragma unroll
        for (int j = 0; j < 2; ++j)
#pragma unroll
            for (int kt = 0; kt < 4; ++kt) {
                int nt = g * 8 + 2 * w + j;
                wA[g][j][kt] = __builtin_bit_cast(bf16x8, F4[(TG1 + nt * 4 + kt) * 64 + lane]);
                wBi[g][j][kt] = __builtin_bit_cast(bf16x8, F4[(TG2 + nt * 4 + kt) * 64 + lane]);
                wBh[g][j][kt] = __builtin_bit_cast(bf16x8, F4[(TG3 + nt * 4 + kt) * 64 + lane]);
            }
    float mb1_c[2] = {mb1g[w * 32 + lr], mb1g[w * 32 + 16 + lr]};
    const float dbC_l = dbCg[lr];
    const float mbE_l = mbEg[lr];
    float loss = 0.f;
    __syncthreads();

    const int r = lr;  // A-operand row for this lane
    for (int t = 0; t <= T_STEPS; ++t) {
        const int cur = t & 1, nxt = cur ^ 1;
        const char* h0c = smem + H0_OFF + cur * 4352;
        char* h0n = smem + H0_OFF + nxt * 4352;
        const char* h1c = smem + H1_OFF + cur * 4352;
        char* h1n = smem + H1_OFF + nxt * 4352;
        const int s = t & (CHUNK - 1);

        // ---- chunk refill every 32 steps (coalesced along t) ----
        if ((t & (CHUNK - 1)) == 0) {
            if (t < T_STEPS) {
                for (int q = 0; q < 32; ++q) {
                    int pair = w * 64 + q * 2 + (lane >> 5);
                    int rr2 = pair >> 4, ch = pair & 15, ss = lane & 31;
                    float v = u[(r0 + rr2) * 16384 + ch * 1024 + t + ss];
                    *(ushort16_t*)(smem + UCH_OFF + ss * 768 + rr2 * 48 + ch * 2) = f2bf(v);
                }
            }
            for (int q = 0; q < 32; ++q) {
                int pair = w * 64 + q * 2 + (lane >> 5);
                int rr2 = pair >> 4, ch = pair & 15, ss = lane & 31;
                int gt = t - 1 + ss;
                if (gt >= 0 && gt < T_STEPS) {
                    float v = yg[(r0 + rr2) * 16384 + ch * 1024 + gt];
                    *(ushort16_t*)(smem + YCH_OFF + ss * 768 + rr2 * 48 + ch * 2) = f2bf(v);
                }
            }
            __syncthreads();
        }

        // ================= I1: GRU0(t)  ||  menn-L1(t-1) =================
        if (t < T_STEPS) {
            const char* ainp_p = (lg < 2) ? (smem + UCH_OFF + s * 768 + r * 48 + lg * 16)
                                          : (smem + XB_OFF + r * 48 + (lg - 2) * 16);
            bf16x8 a_inp = ldsAF(ainp_p);
            bf16x8 ah[4];
#pragma unroll
            for (int kt = 0; kt < 4; ++kt) ah[kt] = ldsAF(h0c + r * 272 + kt * 64 + lg * 16);
            f32x4 aR[2], aZ[2], aNi[2], aNh[2];
#pragma unroll
            for (int j = 0; j < 2; ++j) {
                bf16x8 b0r = ldsAF(smem + WL_OFF + (0 * 8 + 2 * w + j) * 1024 + lane * 16);
                bf16x8 b0z = ldsAF(smem + WL_OFF + (1 * 8 + 2 * w + j) * 1024 + lane * 16);
                bf16x8 b0n = ldsAF(smem + WL_OFF + (2 * 8 + 2 * w + j) * 1024 + lane * 16);
                aR[j] = mfma16(a_inp, b0r, zero);
                aZ[j] = mfma16(a_inp, b0z, zero);
                aNi[j] = mfma16(a_inp, b0n, zero);
                aNh[j] = zero;
#pragma unroll
                for (int kt = 0; kt < 4; ++kt) {
                    aR[j] = mfma16(ah[kt], wA[0][j][kt], aR[j]);
                    aZ[j] = mfma16(ah[kt], wA[1][j][kt], aZ[j]);
                    aNh[j] = mfma16(ah[kt], wA[2][j][kt], aNh[j]);
                }
            }
#pragma unroll
            for (int j = 0; j < 2; ++j) {
                int c = w * 32 + j * 16 + lr;
#pragma unroll
                for (int i = 0; i < 4; ++i) {
                    int row = lg * 4 + i;
                    float hold = bf2f(*(const ushort16_t*)(h0c + row * 272 + c * 2));
                    float rr = sigm(aR[j][i]);
                    float zz = sigm(aZ[j][i]);
                    float nn = tanh_fast(aNi[j][i] + rr * aNh[j][i]);
                    *(ushort16_t*)(h0n + row * 272 + c * 2) = f2bf((1.f - zz) * nn + zz * hold);
                }
            }
        }
        if (t > 0) {  // m1(t-1) = relu([x(t-1), h0n(t-1)] @ mW1^T + mb1);  h0n(t-1) == h0c
            bf16x8 am[5];
            am[0] = ldsAF((lg < 2) ? (smem + XB_OFF + r * 48 + lg * 16) : (h0c + r * 272 + (lg - 2) * 16));
#pragma unroll
            for (int kt = 1; kt < 4; ++kt) am[kt] = ldsAF(h0c + r * 272 + kt * 64 - 32 + lg * 16);
            am[4] = ldsAF((lg < 2) ? (h0c + r * 272 + 224 + lg * 16) : (smem + ZP_OFF + (lg - 2) * 16));
#pragma unroll
            for (int j = 0; j < 2; ++j) {
                f32x4 m = zero;
#pragma unroll
                for (int kt = 0; kt < 5; ++kt)
                    m = mfma16(am[kt], ldsAF(smem + WL_OFF + (29 + (2 * w + j) * 5 + kt) * 1024 + lane * 16), m);
#pragma unroll
                for (int i = 0; i < 4; ++i) {
                    int row = lg * 4 + i;
                    *(ushort16_t*)(smem + M1_OFF + row * 272 + (w * 32 + j * 16 + lr) * 2) =
                        f2bf(fmaxf(m[i] + mb1_c[j], 0.f));
                }
            }
        }
        __syncthreads();

        // ================= I2: GRU1(t)  ||  y_hat/loss(t-1) =================
        if (t < T_STEPS) {
            bf16x8 ag[4], ahh[4];
#pragma unroll
            for (int kt = 0; kt < 4; ++kt) {
                ag[kt] = ldsAF(h0n + r * 272 + kt * 64 + lg * 16);
                ahh[kt] = ldsAF(h1c + r * 272 + kt * 64 + lg * 16);
            }
            f32x4 bR[2], bZ[2], bNi[2], bNh[2];
#pragma unroll
            for (int j = 0; j < 2; ++j) {
                bR[j] = zero; bZ[j] = zero; bNi[j] = zero; bNh[j] = zero;
#pragma unroll
                for (int kt = 0; kt < 4; ++kt) {
                    bR[j] = mfma16(ag[kt], wBi[0][j][kt], bR[j]);
                    bR[j] = mfma16(ahh[kt], wBh[0][j][kt], bR[j]);
                    bZ[j] = mfma16(ag[kt], wBi[1][j][kt], bZ[j]);
                    bZ[j] = mfma16(ahh[kt], wBh[1][j][kt], bZ[j]);
                    bNi[j] = mfma16(ag[kt], wBi[2][j][kt], bNi[j]);
                    bNh[j] = mfma16(ahh[kt], wBh[2][j][kt], bNh[j]);
                }
            }
#pragma unroll
            for (int j = 0; j < 2; ++j) {
                int c = w * 32 + j * 16 + lr;
#pragma unroll
                for (int i = 0; i < 4; ++i) {
                    int row = lg * 4 + i;
                    float hold = bf2f(*(const ushort16_t*)(h1c + row * 272 + c * 2));
                    float rr = sigm(bR[j][i]);
                    float zz = sigm(bZ[j][i]);
                    float nn = tanh_fast(bNi[j][i] + rr * bNh[j][i]);
                    *(ushort16_t*)(h1n + row * 272 + c * 2) = f2bf((1.f - zz) * nn + zz * hold);
                }
            }
        }
        if (t > 0 && w == 3) {  // y_hat(t-1) = m1 @ mE^T + mbE ; loss
            bf16x8 am1[4];
#pragma unroll
            for (int kt = 0; kt < 4; ++kt) am1[kt] = ldsAF(smem + M1_OFF + r * 272 + kt * 64 + lg * 16);
            f32x4 acc = zero;
#pragma unroll
            for (int kt = 0; kt < 4; ++kt)
                acc = mfma16(am1[kt], ldsAF(smem + WL_OFF + (69 + kt) * 1024 + lane * 16), acc);
#pragma unroll
            for (int i = 0; i < 4; ++i) {
                int row = lg * 4 + i;
                float yv = bf2f(*(const ushort16_t*)(smem + YCH_OFF + s * 768 + row * 48 + lr * 2));
                float d = acc[i] + mbE_l - yv;
                loss += d * d;
            }
        }
        __syncthreads();

        // ================= I3: x(t) = [u(t), h1n(t)] @ dC^T + dbC  (wave 0) =================
        if (t < T_STEPS && w == 0) {
            bf16x8 ad[5];
            ad[0] = ldsAF((lg < 2) ? (smem + UCH_OFF + s * 768 + r * 48 + lg * 16)
                                   : (h1n + r * 272 + (lg - 2) * 16));
#pragma unroll
            for (int kt = 1; kt < 4; ++kt) ad[kt] = ldsAF(h1n + r * 272 + kt * 64 - 32 + lg * 16);
            ad[4] = ldsAF((lg < 2) ? (h1n + r * 272 + 224 + lg * 16) : (smem + ZP_OFF + (lg - 2) * 16));
            f32x4 acc = zero;
#pragma unroll
            for (int kt = 0; kt < 5; ++kt)
                acc = mfma16(ad[kt], ldsAF(smem + WL_OFF + (24 + kt) * 1024 + lane * 16), acc);
#pragma unroll
            for (int i = 0; i < 4; ++i) {
                int row = lg * 4 + i;
                *(ushort16_t*)(smem + XB_OFF + row * 48 + lr * 2) = f2bf(acc[i] + dbC_l);
            }
        }
        __syncthreads();
    }

    if (w == 3) {
#pragma unroll
        for (int off = 32; off > 0; off >>= 1) loss += __shfl_down(loss, off, 64);
        if (lane == 0) atomicAdd(out, loss);
    }
}

extern "C" void kernel_launch(void* const* d_in, const int* in_sizes, int n_in,
                              void* d_out, int out_size, void* d_ws, size_t ws_size,
                              hipStream_t stream) {
    const float* u    = (const float*)d_in[0];
    const float* y    = (const float*)d_in[1];
    const float* h0   = (const float*)d_in[2];
    const float* Wih0 = (const float*)d_in[3];
    const float* Whh0 = (const float*)d_in[4];
    const float* Wih1 = (const float*)d_in[5];
    const float* Whh1 = (const float*)d_in[6];
    const float* dW1  = (const float*)d_in[7];
    const float* db1  = (const float*)d_in[8];
    const float* dW2  = (const float*)d_in[9];
    const float* db2  = (const float*)d_in[10];
    const float* mW1  = (const float*)d_in[11];
    const float* mb1  = (const float*)d_in[12];
    const float* mW2  = (const float*)d_in[13];
    const float* mb2  = (const float*)d_in[14];
    const float* mW3  = (const float*)d_in[15];
    const float* mb3  = (const float*)d_in[16];
    float* out = (float*)d_out;
    char* ws = (char*)d_ws;

    prep1<<<dim3(18), dim3(256), 0, stream>>>(dW1, db1, dW2, db2, mW2, mb2, mW3, mb3, ws, out);
    prep2<<<dim3(NT_TOT), dim3(64), 0, stream>>>(Wih0, Whh0, Wih1, Whh1, mW1, ws);
    rnn_main<<<dim3(16), dim3(256), 0, stream>>>(u, y, h0, ws, mb1,
                                                 (const float*)(ws + SC_DBC),
                                                 (const float*)(ws + SC_MBE), out);
}

// Round 3
// 3326.855 us; speedup vs baseline: 1.7197x; 1.3347x over previous
//
#include <hip/hip_runtime.h>

typedef __bf16 bf16x8 __attribute__((ext_vector_type(8)));
typedef float f32x4 __attribute__((ext_vector_type(4)));
typedef unsigned int uint32;
typedef unsigned short ushort16_t;

#define T_STEPS 1024
#define CHUNK 32

// ---------------- LDS layout (byte offsets), all 16B aligned ----------------
#define H0_OFF   0              // 2 ping-pong [16][272B] (16 rows x 128 bf16 + 16B pad)
#define H1_OFF   8704
#define M1_OFF   17408          // [16][272B]
#define XB_OFF   21760          // [16][48B]  (16 rows x 16 bf16, stride 48)
#define ZP_OFF   22528          // 64B zero block
#define UCH_OFF  22592          // [32 s][16 r][48B]  u chunk (bf16); also weight-stage scratch
#define YCH_OFF  47168          // [32 s][16 r][48B]  y chunk (bf16)
#define WL_OFF   71744          // 73 weight tiles x 1024B (G0:0..23, G4:24..28, G5:29..68, G6:69..72)
#define LDS_BYTES 146496

// ---------------- global frag buffer: tile bases (tile = 512 bf16 = 1KB) ----
#define TG0 0     // Wih0 [384,32]   KT=1 NT=24
#define TG1 24    // Whh0 [384,128]  KT=4 NT=24
#define TG2 120   // Wih1 [384,128]
#define TG3 216   // Whh1 [384,128]
#define TG4 312   // dC   [16,144->160] KT=5 NT=1
#define TG5 317   // mW1  [128,144->160] KT=5 NT=8
#define TG6 357   // mE   [16,128]   KT=4 NT=1
#define NT_TOT 361
// fp32 scratch (byte offsets in d_ws)
#define SC_DC  369664   // dC fp32 [16][144]
#define SC_ME  378880   // mE fp32 [16][128]
#define SC_DBC 387072   // dbC fp32 [16]
#define SC_MBE 387136   // mbE fp32 [16]

static __device__ __forceinline__ ushort16_t f2bf(float f) {
    uint32 u = __builtin_bit_cast(uint32, f);
    return (ushort16_t)((u + 0x7FFFu + ((u >> 16) & 1u)) >> 16);
}
static __device__ __forceinline__ float bf2f(ushort16_t h) {
    uint32 u = ((uint32)h) << 16;
    return __builtin_bit_cast(float, u);
}
static __device__ __forceinline__ float sigm(float x) { return 1.f / (1.f + __expf(-x)); }
static __device__ __forceinline__ float tanh_fast(float x) {
    x = fmaxf(fminf(x, 30.f), -30.f);
    float e = __expf(-2.f * x);
    return (1.f - e) / (1.f + e);
}
static __device__ __forceinline__ f32x4 mfma16(bf16x8 a, bf16x8 b, f32x4 c) {
    return __builtin_amdgcn_mfma_f32_16x16x32_bf16(a, b, c, 0, 0, 0);
}
static __device__ __forceinline__ bf16x8 ldsAF(const char* p) {
    return __builtin_bit_cast(bf16x8, *(const uint4*)p);
}

// ---------------- prep1: combined matrices + biases (fp32), zero d_out ----------------
__global__ void prep1(const float* __restrict__ dW1, const float* __restrict__ db1,
                      const float* __restrict__ dW2, const float* __restrict__ db2,
                      const float* __restrict__ mW2, const float* __restrict__ mb2,
                      const float* __restrict__ mW3, const float* __restrict__ mb3,
                      char* __restrict__ ws, float* __restrict__ out) {
    int id = blockIdx.x * 256 + threadIdx.x;
    if (id == 0) *out = 0.f;
    if (id < 2304) {                       // dC[n][k] = sum_h dW2[n][h]*dW1[h][k]
        int n = id / 144, k = id % 144;
        float s = 0.f;
        for (int h = 0; h < 128; ++h) s += dW2[n * 128 + h] * dW1[h * 144 + k];
        ((float*)(ws + SC_DC))[id] = s;
    } else if (id < 4352) {                // mE[n][k] = sum_h mW3[n][h]*mW2[h][k]
        int e = id - 2304, n = e / 128, k = e % 128;
        float s = 0.f;
        for (int h = 0; h < 128; ++h) s += mW3[n * 128 + h] * mW2[h * 128 + k];
        ((float*)(ws + SC_ME))[e] = s;
    } else if (id < 4368) {                // dbC = dW2@db1 + db2
        int n = id - 4352;
        float s = db2[n];
        for (int h = 0; h < 128; ++h) s += dW2[n * 128 + h] * db1[h];
        ((float*)(ws + SC_DBC))[n] = s;
    } else if (id < 4384) {                // mbE = mW3@mb2 + mb3
        int n = id - 4368;
        float s = mb3[n];
        for (int h = 0; h < 128; ++h) s += mW3[n * 128 + h] * mb2[h];
        ((float*)(ws + SC_MBE))[n] = s;
    }
}

// ---------------- prep2: pack all weights into MFMA B-fragment order (bf16) ----------------
__global__ void prep2(const float* __restrict__ W0, const float* __restrict__ W1,
                      const float* __restrict__ W2, const float* __restrict__ W3,
                      const float* __restrict__ W5, char* __restrict__ ws) {
    const int tt = blockIdx.x;     // 0..360
    const int lane = threadIdx.x;  // 0..63
    const int cum[8] = {TG0, TG1, TG2, TG3, TG4, TG5, TG6, NT_TOT};
    const int Kreal[7] = {32, 128, 128, 128, 144, 144, 128};
    const int KT[7] = {1, 4, 4, 4, 5, 5, 4};
    const float* Ws[7] = {W0, W1, W2, W3, (const float*)(ws + SC_DC), W5, (const float*)(ws + SC_ME)};
    int g = 0;
    while (tt >= cum[g + 1]) ++g;
    const int tl = tt - cum[g];
    const int kt = tl % KT[g];
    const int n = (tl / KT[g]) * 16 + (lane & 15);
    const float* W = Ws[g];
    ushort16_t* o = (ushort16_t*)ws + tt * 512 + lane * 8;
#pragma unroll
    for (int j = 0; j < 8; ++j) {
        int k = kt * 32 + (lane >> 4) * 8 + j;
        o[j] = (k < Kreal[g]) ? f2bf(W[n * Kreal[g] + k]) : (ushort16_t)0;
    }
}

// ---------------- main: 16 WG x 512 thr (8 waves, 2 waves/SIMD, 256-VGPR budget) ----------
__global__ __launch_bounds__(512, 2) void rnn_main(
    const float* __restrict__ u, const float* __restrict__ yg, const float* __restrict__ h0g,
    const char* __restrict__ ws, const float* __restrict__ mb1g,
    const float* __restrict__ dbCg, const float* __restrict__ mbEg,
    float* __restrict__ out) {
    __shared__ __align__(16) char smem[LDS_BYTES];
    const int tid = threadIdx.x;
    const int lane = tid & 63;
    const int w = tid >> 6;       // wave 0..7: owns cols [w*16, w*16+16)
    const int lr = lane & 15;
    const int lg = lane >> 4;
    const int r0 = blockIdx.x * 16;
    const uint4* F4 = (const uint4*)ws;
    const f32x4 zero = {0.f, 0.f, 0.f, 0.f};

    // ---- init: zero xbuf+zeroblock, load h0 -> LDS bf16, copy LDS-resident weights ----
    for (int i = tid; i < (768 + 64) / 4; i += 512) *(uint32*)(smem + XB_OFF + i * 4) = 0;
    for (int i = tid; i < 1024; i += 512) {  // 2 layers x 16 rows x 32 float4
        int lay = i >> 9, rem = i & 511, rr = rem >> 5, k4 = rem & 31;
        float4 v = *(const float4*)(h0g + (lay * 256 + r0 + rr) * 128 + k4 * 4);
        uint2 pk;
        pk.x = (uint32)f2bf(v.x) | ((uint32)f2bf(v.y) << 16);
        pk.y = (uint32)f2bf(v.z) | ((uint32)f2bf(v.w) << 16);
        *(uint2*)(smem + H0_OFF + lay * 8704 + rr * 272 + k4 * 8) = pk;
    }
    for (int i = tid; i < 73 * 64; i += 512) {  // G0,G4,G5,G6 -> LDS (loop-resident weights)
        int li = i >> 6, ln2 = i & 63;
        int gt2 = (li < 24) ? li : (li < 29) ? TG4 + (li - 24) : (li < 69) ? TG5 + (li - 29) : TG6 + (li - 69);
        *((uint4*)(smem + WL_OFF) + i) = F4[gt2 * 64 + ln2];
    }
    __syncthreads();

    // ---- per-wave register-resident weights, staged THROUGH LDS so the compiler
    //      cannot rematerialize the loads inside the t-loop (36 tiles = 144 VGPR) ----
    // wW[mat][gate][kt]: mat 0=Whh0, 1=Wih1, 2=Whh1; tile rel index = mat*96 + gate*32 + w*4 + kt
    bf16x8 wW[3][3][4];
    for (int p = 0; p < 6; ++p) {
        // stage 48 tiles (48KB) of the G1..G3 range into the chunk area
        for (int i = tid; i < 3072; i += 512)
            *((uint4*)(smem + UCH_OFF) + i) = F4[(TG1 + p * 48) * 64 + i];
        __syncthreads();
#pragma unroll
        for (int mat = 0; mat < 3; ++mat)
#pragma unroll
            for (int gg = 0; gg < 3; ++gg) {
                int rel0 = mat * 96 + gg * 32 + w * 4;   // 4-tile block, wholly inside one window
                if (rel0 >= p * 48 && rel0 < p * 48 + 48) {
#pragma unroll
                    for (int kt = 0; kt < 4; ++kt)
                        wW[mat][gg][kt] = ldsAF(smem + UCH_OFF + (rel0 - p * 48 + kt) * 1024 + lane * 16);
                }
            }
        __syncthreads();
    }

    const float mb1_c = mb1g[w * 16 + lr];
    const float dbC_l = dbCg[lr];
    const float mbE_l = mbEg[lr];
    float loss = 0.f;

    const int r = lr;  // A-operand row for this lane
    for (int t = 0; t <= T_STEPS; ++t) {
        const int cur = t & 1, nxt = cur ^ 1;
        const char* h0c = smem + H0_OFF + cur * 4352;
        char* h0n = smem + H0_OFF + nxt * 4352;
        const char* h1c = smem + H1_OFF + cur * 4352;
        char* h1n = smem + H1_OFF + nxt * 4352;
        const int s = t & (CHUNK - 1);

        // ---- chunk refill every 32 steps (coalesced along t) ----
        if ((t & (CHUNK - 1)) == 0) {
            if (t < T_STEPS) {
                for (int q = 0; q < 16; ++q) {
                    int pair = w * 32 + q * 2 + (lane >> 5);
                    int rr2 = pair >> 4, ch = pair & 15, ss = lane & 31;
                    float v = u[(r0 + rr2) * 16384 + ch * 1024 + t + ss];
                    *(ushort16_t*)(smem + UCH_OFF + ss * 768 + rr2 * 48 + ch * 2) = f2bf(v);
                }
            }
            for (int q = 0; q < 16; ++q) {
                int pair = w * 32 + q * 2 + (lane >> 5);
                int rr2 = pair >> 4, ch = pair & 15, ss = lane & 31;
                int gt = t - 1 + ss;
                if (gt >= 0 && gt < T_STEPS) {
                    float v = yg[(r0 + rr2) * 16384 + ch * 1024 + gt];
                    *(ushort16_t*)(smem + YCH_OFF + ss * 768 + rr2 * 48 + ch * 2) = f2bf(v);
                }
            }
            __syncthreads();
        }

        // ================= I1: GRU0(t)  ||  menn-L1(t-1) =================
        if (t < T_STEPS) {
            const char* ainp_p = (lg < 2) ? (smem + UCH_OFF + s * 768 + r * 48 + lg * 16)
                                          : (smem + XB_OFF + r * 48 + (lg - 2) * 16);
            bf16x8 a_inp = ldsAF(ainp_p);
            bf16x8 ah[4];
#pragma unroll
            for (int kt = 0; kt < 4; ++kt) ah[kt] = ldsAF(h0c + r * 272 + kt * 64 + lg * 16);
            // split chains: input-part (single mfma) vs h-part (4-chain)
            f32x4 aRi = mfma16(a_inp, ldsAF(smem + WL_OFF + (0 * 8 + w) * 1024 + lane * 16), zero);
            f32x4 aZi = mfma16(a_inp, ldsAF(smem + WL_OFF + (1 * 8 + w) * 1024 + lane * 16), zero);
            f32x4 aNi = mfma16(a_inp, ldsAF(smem + WL_OFF + (2 * 8 + w) * 1024 + lane * 16), zero);
            f32x4 aRh = zero, aZh = zero, aNh = zero;
#pragma unroll
            for (int kt = 0; kt < 4; ++kt) {
                aRh = mfma16(ah[kt], wW[0][0][kt], aRh);
                aZh = mfma16(ah[kt], wW[0][1][kt], aZh);
                aNh = mfma16(ah[kt], wW[0][2][kt], aNh);
            }
            const int c = w * 16 + lr;
#pragma unroll
            for (int i = 0; i < 4; ++i) {
                int row = lg * 4 + i;
                float hold = bf2f(*(const ushort16_t*)(h0c + row * 272 + c * 2));
                float rr = sigm(aRi[i] + aRh[i]);
                float zz = sigm(aZi[i] + aZh[i]);
                float nn = tanh_fast(aNi[i] + rr * aNh[i]);
                *(ushort16_t*)(h0n + row * 272 + c * 2) = f2bf((1.f - zz) * nn + zz * hold);
            }
        }
        if (t > 0) {  // m1(t-1) = relu([x(t-1), h0n(t-1)] @ mW1^T + mb1);  h0n(t-1) == h0c
            bf16x8 am[5];
            am[0] = ldsAF((lg < 2) ? (smem + XB_OFF + r * 48 + lg * 16) : (h0c + r * 272 + (lg - 2) * 16));
#pragma unroll
            for (int kt = 1; kt < 4; ++kt) am[kt] = ldsAF(h0c + r * 272 + kt * 64 - 32 + lg * 16);
            am[4] = ldsAF((lg < 2) ? (h0c + r * 272 + 224 + lg * 16) : (smem + ZP_OFF + (lg - 2) * 16));
            f32x4 m = zero;
#pragma unroll
            for (int kt = 0; kt < 5; ++kt)
                m = mfma16(am[kt], ldsAF(smem + WL_OFF + (29 + w * 5 + kt) * 1024 + lane * 16), m);
#pragma unroll
            for (int i = 0; i < 4; ++i) {
                int row = lg * 4 + i;
                *(ushort16_t*)(smem + M1_OFF + row * 272 + (w * 16 + lr) * 2) =
                    f2bf(fmaxf(m[i] + mb1_c, 0.f));
            }
        }
        __syncthreads();

        // ================= I2: GRU1(t)  ||  y_hat/loss(t-1) =================
        if (t < T_STEPS) {
            bf16x8 ag[4], ahh[4];
#pragma unroll
            for (int kt = 0; kt < 4; ++kt) {
                ag[kt] = ldsAF(h0n + r * 272 + kt * 64 + lg * 16);
                ahh[kt] = ldsAF(h1c + r * 272 + kt * 64 + lg * 16);
            }
            f32x4 bRi = zero, bRh = zero, bZi = zero, bZh = zero, bNi = zero, bNh = zero;
#pragma unroll
            for (int kt = 0; kt < 4; ++kt) {
                bRi = mfma16(ag[kt], wW[1][0][kt], bRi);
                bRh = mfma16(ahh[kt], wW[2][0][kt], bRh);
                bZi = mfma16(ag[kt], wW[1][1][kt], bZi);
                bZh = mfma16(ahh[kt], wW[2][1][kt], bZh);
                bNi = mfma16(ag[kt], wW[1][2][kt], bNi);
                bNh = mfma16(ahh[kt], wW[2][2][kt], bNh);
            }
            const int c = w * 16 + lr;
#pragma unroll
            for (int i = 0; i < 4; ++i) {
                int row = lg * 4 + i;
                float hold = bf2f(*(const ushort16_t*)(h1c + row * 272 + c * 2));
                float rr = sigm(bRi[i] + bRh[i]);
                float zz = sigm(bZi[i] + bZh[i]);
                float nn = tanh_fast(bNi[i] + rr * bNh[i]);
                *(ushort16_t*)(h1n + row * 272 + c * 2) = f2bf((1.f - zz) * nn + zz * hold);
            }
        }
        if (t > 0 && w == 7) {  // y_hat(t-1) = m1 @ mE^T + mbE ; loss
            bf16x8 am1[4];
#pragma unroll
            for (int kt = 0; kt < 4; ++kt) am1[kt] = ldsAF(smem + M1_OFF + r * 272 + kt * 64 + lg * 16);
            f32x4 acc = zero;
#pragma unroll
            for (int kt = 0; kt < 4; ++kt)
                acc = mfma16(am1[kt], ldsAF(smem + WL_OFF + (69 + kt) * 1024 + lane * 16), acc);
#pragma unroll
            for (int i = 0; i < 4; ++i) {
                int row = lg * 4 + i;
                float yv = bf2f(*(const ushort16_t*)(smem + YCH_OFF + s * 768 + row * 48 + lr * 2));
                float d = acc[i] + mbE_l - yv;
                loss += d * d;
            }
        }
        __syncthreads();

        // ================= I3: x(t) = [u(t), h1n(t)] @ dC^T + dbC  (wave 0) =================
        if (t < T_STEPS && w == 0) {
            bf16x8 ad[5];
            ad[0] = ldsAF((lg < 2) ? (smem + UCH_OFF + s * 768 + r * 48 + lg * 16)
                                   : (h1n + r * 272 + (lg - 2) * 16));
#pragma unroll
            for (int kt = 1; kt < 4; ++kt) ad[kt] = ldsAF(h1n + r * 272 + kt * 64 - 32 + lg * 16);
            ad[4] = ldsAF((lg < 2) ? (h1n + r * 272 + 224 + lg * 16) : (smem + ZP_OFF + (lg - 2) * 16));
            f32x4 acc = zero;
#pragma unroll
            for (int kt = 0; kt < 5; ++kt)
                acc = mfma16(ad[kt], ldsAF(smem + WL_OFF + (24 + kt) * 1024 + lane * 16), acc);
#pragma unroll
            for (int i = 0; i < 4; ++i) {
                int row = lg * 4 + i;
                *(ushort16_t*)(smem + XB_OFF + row * 48 + lr * 2) = f2bf(acc[i] + dbC_l);
            }
        }
        __syncthreads();
    }

    if (w == 7) {
#pragma unroll
        for (int off = 32; off > 0; off >>= 1) loss += __shfl_down(loss, off, 64);
        if (lane == 0) atomicAdd(out, loss);
    }
}

extern "C" void kernel_launch(void* const* d_in, const int* in_sizes, int n_in,
                              void* d_out, int out_size, void* d_ws, size_t ws_size,
                              hipStream_t stream) {
    const float* u    = (const float*)d_in[0];
    const float* y    = (const float*)d_in[1];
    const float* h0   = (const float*)d_in[2];
    const float* Wih0 = (const float*)d_in[3];
    const float* Whh0 = (const float*)d_in[4];
    const float* Wih1 = (const float*)d_in[5];
    const float* Whh1 = (const float*)d_in[6];
    const float* dW1  = (const float*)d_in[7];
    const float* db1  = (const float*)d_in[8];
    const float* dW2  = (const float*)d_in[9];
    const float* db2  = (const float*)d_in[10];
    const float* mW1  = (const float*)d_in[11];
    const float* mb1  = (const float*)d_in[12];
    const float* mW2  = (const float*)d_in[13];
    const float* mb2  = (const float*)d_in[14];
    const float* mW3  = (const float*)d_in[15];
    const float* mb3  = (const float*)d_in[16];
    float* out = (float*)d_out;
    char* ws = (char*)d_ws;

    prep1<<<dim3(18), dim3(256), 0, stream>>>(dW1, db1, dW2, db2, mW2, mb2, mW3, mb3, ws, out);
    prep2<<<dim3(NT_TOT), dim3(64), 0, stream>>>(Wih0, Whh0, Wih1, Whh1, mW1, ws);
    rnn_main<<<dim3(16), dim3(512), 0, stream>>>(u, y, h0, ws, mb1,
                                                 (const float*)(ws + SC_DBC),
                                                 (const float*)(ws + SC_MBE), out);
}

// Round 4
// 2778.346 us; speedup vs baseline: 2.0592x; 1.1974x over previous
//
#include <hip/hip_runtime.h>

typedef __bf16 bf16x8 __attribute__((ext_vector_type(8)));
typedef float f32x4 __attribute__((ext_vector_type(4)));
typedef unsigned int uint32;
typedef unsigned short u16;

#define T_STEPS 1024

// ---------------- LDS layout (byte offsets), 16B aligned ----------------
#define H0_OFF   0              // 2 ping-pong [16 rows][272B] (128 bf16 + 16B pad)
#define H1_OFF   8704
#define M1_OFF   17408          // [16][272B]
#define UCH_OFF  21760          // [32 s][16 r][48B] u chunk bf16 (also weight-stage scratch)
#define YCH_OFF  46336          // [32 s][16 r][48B] y chunk bf16
#define WL_OFF   70912          // 73 tiles x 1024B: [0..23]=Wih0, [24..28]=dC, [29..68]=mW1, [69..72]=mE
#define LDS_BYTES 145664

// ---------------- global frag buffer tiles (1 tile = 512 bf16 = 1KB) ----
#define TG0 0     // Wih0 [384,32]   KT=1 NT=24
#define TG1 24    // Whh0 [384,128]  KT=4 NT=24
#define TG2 120   // Wih1 [384,128]
#define TG3 216   // Whh1 [384,128]
#define TG4 312   // dC   [16,160]   KT=5 NT=1
#define TG5 317   // mW1  [128,160]  KT=5 NT=8
#define TG6 357   // mE   [16,128]   KT=4 NT=1
#define NT_TOT 361
#define SC_DC  369664
#define SC_ME  378880
#define SC_DBC 387072
#define SC_MBE 387136

static __device__ __forceinline__ u16 f2bf(float f) {
    uint32 u = __builtin_bit_cast(uint32, f);
    return (u16)((u + 0x7FFFu + ((u >> 16) & 1u)) >> 16);
}
static __device__ __forceinline__ float bf2f(u16 h) {
    uint32 u = ((uint32)h) << 16;
    return __builtin_bit_cast(float, u);
}
static __device__ __forceinline__ uint32 cvtpk(float a, float b) {
    uint32 r;
    asm("v_cvt_pk_bf16_f32 %0, %1, %2" : "=v"(r) : "v"(a), "v"(b));
    return r;
}
static __device__ __forceinline__ float sigm(float x) {
    return __builtin_amdgcn_rcpf(1.f + __builtin_amdgcn_exp2f(x * -1.4426950408889634f));
}
static __device__ __forceinline__ float tanh_fast(float x) {
    float xm = fmaxf(x, -30.f);
    float e = __builtin_amdgcn_exp2f(xm * -2.8853900817779268f);
    return fmaf(2.f, __builtin_amdgcn_rcpf(e + 1.f), -1.f);
}
static __device__ __forceinline__ f32x4 mfma16(bf16x8 a, bf16x8 b, f32x4 c) {
    return __builtin_amdgcn_mfma_f32_16x16x32_bf16(a, b, c, 0, 0, 0);
}
static __device__ __forceinline__ bf16x8 ldsAF(const char* p) {
    return __builtin_bit_cast(bf16x8, *(const uint4*)p);
}

// ---------------- prep1: combined matrices + biases (fp32), zero d_out ----------------
__global__ void prep1(const float* __restrict__ dW1, const float* __restrict__ db1,
                      const float* __restrict__ dW2, const float* __restrict__ db2,
                      const float* __restrict__ mW2, const float* __restrict__ mb2,
                      const float* __restrict__ mW3, const float* __restrict__ mb3,
                      char* __restrict__ ws, float* __restrict__ out) {
    int id = blockIdx.x * 256 + threadIdx.x;
    if (id == 0) *out = 0.f;
    if (id < 2304) {                       // dC[n][k] = sum_h dW2[n][h]*dW1[h][k]
        int n = id / 144, k = id % 144;
        float s = 0.f;
        for (int h = 0; h < 128; ++h) s += dW2[n * 128 + h] * dW1[h * 144 + k];
        ((float*)(ws + SC_DC))[id] = s;
    } else if (id < 4352) {                // mE[n][k] = sum_h mW3[n][h]*mW2[h][k]
        int e = id - 2304, n = e / 128, k = e % 128;
        float s = 0.f;
        for (int h = 0; h < 128; ++h) s += mW3[n * 128 + h] * mW2[h * 128 + k];
        ((float*)(ws + SC_ME))[e] = s;
    } else if (id < 4368) {                // dbC = dW2@db1 + db2
        int n = id - 4352;
        float s = db2[n];
        for (int h = 0; h < 128; ++h) s += dW2[n * 128 + h] * db1[h];
        ((float*)(ws + SC_DBC))[n] = s;
    } else if (id < 4384) {                // mbE = mW3@mb2 + mb3
        int n = id - 4368;
        float s = mb3[n];
        for (int h = 0; h < 128; ++h) s += mW3[n * 128 + h] * mb2[h];
        ((float*)(ws + SC_MBE))[n] = s;
    }
}

// ---------------- prep2: pack weights into MFMA B-fragment order (bf16) ----------------
__global__ void prep2(const float* __restrict__ W0, const float* __restrict__ W1,
                      const float* __restrict__ W2, const float* __restrict__ W3,
                      const float* __restrict__ W5, char* __restrict__ ws) {
    const int tt = blockIdx.x;     // 0..360
    const int lane = threadIdx.x;  // 0..63
    const int cum[8] = {TG0, TG1, TG2, TG3, TG4, TG5, TG6, NT_TOT};
    const int Kreal[7] = {32, 128, 128, 128, 144, 144, 128};
    const int KT[7] = {1, 4, 4, 4, 5, 5, 4};
    const float* Ws[7] = {W0, W1, W2, W3, (const float*)(ws + SC_DC), W5, (const float*)(ws + SC_ME)};
    int g = 0;
    while (tt >= cum[g + 1]) ++g;
    const int tl = tt - cum[g];
    const int kt = tl % KT[g];
    const int n = (tl / KT[g]) * 16 + (lane & 15);
    const float* W = Ws[g];
    u16* o = (u16*)ws + tt * 512 + lane * 8;
#pragma unroll
    for (int j = 0; j < 8; ++j) {
        int k = kt * 32 + (lane >> 4) * 8 + j;
        o[j] = (k < Kreal[g]) ? f2bf(W[n * Kreal[g] + k]) : (u16)0;
    }
}

// ---------------- main: 16 WG x 512 thr (8 waves, 2 waves/SIMD) ----------
__global__ __launch_bounds__(512, 2) void rnn_main(
    const float* __restrict__ u, const float* __restrict__ yg, const float* __restrict__ h0g,
    const char* __restrict__ ws, const float* __restrict__ mb1g,
    const float* __restrict__ dbCg, const float* __restrict__ mbEg,
    float* __restrict__ out) {
    __shared__ __align__(16) char smem[LDS_BYTES];
    const int tid = threadIdx.x;
    const int lane = tid & 63;
    const int w = tid >> 6;       // wave 0..7: owns cols [w*16, w*16+16)
    const int lr = lane & 15;
    const int lg = lane >> 4;
    const int r0 = blockIdx.x * 16;
    const uint4* F4 = (const uint4*)ws;
    const f32x4 zero = {0.f, 0.f, 0.f, 0.f};
    const bf16x8 z8 = __builtin_bit_cast(bf16x8, (uint4){0u, 0u, 0u, 0u});

    // ---- init: load h0 -> LDS bf16 (buffer 0), copy LDS-resident weights ----
    for (int i = tid; i < 1024; i += 512) {  // 2 layers x 16 rows x 32 float4
        int lay = i >> 9, rem = i & 511, rr = rem >> 5, k4 = rem & 31;
        float4 v = *(const float4*)(h0g + (lay * 256 + r0 + rr) * 128 + k4 * 4);
        uint2 pk;
        pk.x = (uint32)f2bf(v.x) | ((uint32)f2bf(v.y) << 16);
        pk.y = (uint32)f2bf(v.z) | ((uint32)f2bf(v.w) << 16);
        *(uint2*)(smem + H0_OFF + lay * 8704 + rr * 272 + k4 * 8) = pk;
    }
    for (int i = tid; i < 73 * 64; i += 512) {  // Wih0,dC,mW1,mE -> WL
        int li = i >> 6, ln2 = i & 63;
        int gt2 = (li < 24) ? li : (li < 29) ? TG4 + (li - 24) : (li < 69) ? TG5 + (li - 29) : TG6 + (li - 69);
        *((uint4*)(smem + WL_OFF) + i) = F4[gt2 * 64 + ln2];
    }
    __syncthreads();

    // ---- per-wave register weights (Whh0/Wih1/Whh1), staged THROUGH LDS so the
    //      compiler cannot rematerialize the loads inside the t-loop ----
    bf16x8 wW[3][3][4];  // [mat][gate][kt], mat 0=Whh0 1=Wih1 2=Whh1
    for (int p = 0; p < 6; ++p) {
        for (int i = tid; i < 3072; i += 512)
            *((uint4*)(smem + UCH_OFF) + i) = F4[(TG1 + p * 48) * 64 + i];
        __syncthreads();
#pragma unroll
        for (int mat = 0; mat < 3; ++mat)
#pragma unroll
            for (int gg = 0; gg < 3; ++gg) {
                int rel0 = mat * 96 + gg * 32 + w * 4;
                if (rel0 >= p * 48 && rel0 < p * 48 + 48) {
#pragma unroll
                    for (int kt = 0; kt < 4; ++kt)
                        wW[mat][gg][kt] = ldsAF(smem + UCH_OFF + (rel0 - p * 48 + kt) * 1024 + lane * 16);
                }
            }
        __syncthreads();
    }

    // ---- per-lane constants & register-resident hold state ----
    const float mb1_c = mb1g[w * 16 + lr];
    const float mbE_l = mbEg[lr];
    float dbc4[4];
#pragma unroll
    for (int i = 0; i < 4; ++i) dbc4[i] = dbCg[lg * 4 + i];
    float hp0[4], hp1[4];
#pragma unroll
    for (int i = 0; i < 4; ++i) {
        hp0[i] = h0g[(r0 + lg * 4 + i) * 128 + w * 16 + lr];
        hp1[i] = h0g[(256 + r0 + lg * 4 + i) * 128 + w * 16 + lr];
    }
    float loss = 0.f;
    const int c2 = (w * 16 + lr) * 2;
    const int bp0 = (lr + (lg & 1) * 32) * 4;  // bpermute byte-addr of x source lane

    for (int t = 0; t < T_STEPS; ++t) {
        const char* h0c = smem + H0_OFF + (t & 1) * 4352;
        char* h0n = smem + H0_OFF + ((t & 1) ^ 1) * 4352;
        const char* h1c = smem + H1_OFF + (t & 1) * 4352;
        char* h1n = smem + H1_OFF + ((t & 1) ^ 1) * 4352;
        const int s = t & 31, sp = (t - 1) & 31;

        // ======== x(t-1) = [u(t-1)|h1(t-1)] @ dC^T + dbC  (redundant per wave, in-register) ====
        const char* h1r = h1c + lr * 272;
        bf16x8 ad0 = ldsAF((lg < 2) ? (smem + UCH_OFF + sp * 768 + lr * 48 + lg * 16)
                                    : (h1r + (lg - 2) * 16));
        bf16x8 ad1 = ldsAF(h1r + 32 + lg * 16);
        bf16x8 ad2 = ldsAF(h1r + 96 + lg * 16);
        bf16x8 ad3 = ldsAF(h1r + 160 + lg * 16);
        bf16x8 ad4t = ldsAF(h1r + 224 + (lg & 1) * 16);
        bf16x8 ad4 = (lg < 2) ? ad4t : z8;
        f32x4 xa = mfma16(ldsAF(smem + WL_OFF + 24 * 1024 + lane * 16), ad0, zero);
        xa = mfma16(ldsAF(smem + WL_OFF + 25 * 1024 + lane * 16), ad1, xa);
        xa = mfma16(ldsAF(smem + WL_OFF + 26 * 1024 + lane * 16), ad2, xa);
        f32x4 xb = mfma16(ldsAF(smem + WL_OFF + 27 * 1024 + lane * 16), ad3, zero);
        xb = mfma16(ldsAF(smem + WL_OFF + 28 * 1024 + lane * 16), ad4, xb);
        uint32 pk0 = cvtpk(xa[0] + xb[0] + dbc4[0], xa[1] + xb[1] + dbc4[1]);
        uint32 pk1 = cvtpk(xa[2] + xb[2] + dbc4[2], xa[3] + xb[3] + dbc4[3]);
        if (t == 0) { pk0 = 0u; pk1 = 0u; }  // x_prev(0) = 0
        uint32 d0 = (uint32)__builtin_amdgcn_ds_bpermute(bp0, (int)pk0);
        uint32 d1 = (uint32)__builtin_amdgcn_ds_bpermute(bp0, (int)pk1);
        uint32 d2 = (uint32)__builtin_amdgcn_ds_bpermute(bp0 + 64, (int)pk0);
        uint32 d3 = (uint32)__builtin_amdgcn_ds_bpermute(bp0 + 64, (int)pk1);
        bf16x8 xfrag = __builtin_bit_cast(bf16x8, (uint4){d0, d1, d2, d3});

        // ---- chunk refill every 32 steps (after x consumed old slot 31) ----
        if ((t & 31) == 0) {
            __syncthreads();
            for (int q = 0; q < 16; ++q) {
                int pair = w * 32 + q * 2 + (lane >> 5);
                int rr2 = pair >> 4, ch = pair & 15, ss = lane & 31;
                float v = u[(r0 + rr2) * 16384 + ch * 1024 + t + ss];
                *(u16*)(smem + UCH_OFF + ss * 768 + rr2 * 48 + ch * 2) = f2bf(v);
            }
            for (int q = 0; q < 16; ++q) {
                int pair = w * 32 + q * 2 + (lane >> 5);
                int rr2 = pair >> 4, ch = pair & 15, ss = lane & 31;
                int gt = t - 1 + ss;
                if (gt >= 0 && gt < T_STEPS) {
                    float v = yg[(r0 + rr2) * 16384 + ch * 1024 + gt];
                    *(u16*)(smem + YCH_OFF + ss * 768 + rr2 * 48 + ch * 2) = f2bf(v);
                }
            }
            __syncthreads();
        }

        // ================= PHASE 1: GRU0(t) + m1(t-1) =================
        bf16x8 ufrag = ldsAF(smem + UCH_OFF + s * 768 + lr * 48 + (lg & 1) * 16);
        bf16x8 a_inp = (lg < 2) ? ufrag : xfrag;
        const char* h0r = h0c + lr * 272;
        bf16x8 ah0 = ldsAF(h0r + lg * 16);
        bf16x8 ah1 = ldsAF(h0r + 64 + lg * 16);
        bf16x8 ah2 = ldsAF(h0r + 128 + lg * 16);
        bf16x8 ah3 = ldsAF(h0r + 192 + lg * 16);
        bf16x8 b0r = ldsAF(smem + WL_OFF + (0 * 8 + w) * 1024 + lane * 16);
        bf16x8 b0z = ldsAF(smem + WL_OFF + (1 * 8 + w) * 1024 + lane * 16);
        bf16x8 b0n = ldsAF(smem + WL_OFF + (2 * 8 + w) * 1024 + lane * 16);
        f32x4 rA = mfma16(ah0, wW[0][0][0], zero);
        rA = mfma16(ah1, wW[0][0][1], rA);
        rA = mfma16(a_inp, b0r, rA);
        f32x4 rB = mfma16(ah2, wW[0][0][2], zero);
        rB = mfma16(ah3, wW[0][0][3], rB);
        f32x4 zA = mfma16(ah0, wW[0][1][0], zero);
        zA = mfma16(ah1, wW[0][1][1], zA);
        zA = mfma16(a_inp, b0z, zA);
        f32x4 zB = mfma16(ah2, wW[0][1][2], zero);
        zB = mfma16(ah3, wW[0][1][3], zB);
        f32x4 nI = mfma16(a_inp, b0n, zero);
        f32x4 nA = mfma16(ah0, wW[0][2][0], zero);
        nA = mfma16(ah1, wW[0][2][1], nA);
        f32x4 nB = mfma16(ah2, wW[0][2][2], zero);
        nB = mfma16(ah3, wW[0][2][3], nB);
        // m1(t-1) = relu([x(t-1), h0(t-1)] @ mW1^T + mb1)
        bf16x8 t0 = ldsAF(h0r + (lg & 1) * 16);
        bf16x8 am0 = (lg < 2) ? xfrag : t0;
        bf16x8 am1 = ldsAF(h0r + 32 + lg * 16);
        bf16x8 am2 = ldsAF(h0r + 96 + lg * 16);
        bf16x8 am3 = ldsAF(h0r + 160 + lg * 16);
        bf16x8 am4t = ldsAF(h0r + 224 + (lg & 1) * 16);
        bf16x8 am4 = (lg < 2) ? am4t : z8;
        f32x4 mA = mfma16(am1, ldsAF(smem + WL_OFF + (29 + w * 5 + 1) * 1024 + lane * 16), zero);
        mA = mfma16(am2, ldsAF(smem + WL_OFF + (29 + w * 5 + 2) * 1024 + lane * 16), mA);
        mA = mfma16(am0, ldsAF(smem + WL_OFF + (29 + w * 5 + 0) * 1024 + lane * 16), mA);
        f32x4 mB = mfma16(am3, ldsAF(smem + WL_OFF + (29 + w * 5 + 3) * 1024 + lane * 16), zero);
        mB = mfma16(am4, ldsAF(smem + WL_OFF + (29 + w * 5 + 4) * 1024 + lane * 16), mB);
#pragma unroll
        for (int i = 0; i < 4; ++i) {
            float rr = sigm(rA[i] + rB[i]);
            float zz = sigm(zA[i] + zB[i]);
            float nn = tanh_fast(fmaf(rr, nA[i] + nB[i], nI[i]));
            float hnew = fmaf(zz, hp0[i] - nn, nn);
            hp0[i] = hnew;
            *(u16*)(h0n + (lg * 4 + i) * 272 + c2) = (u16)cvtpk(hnew, hnew);
            float mv = fmaxf(mA[i] + mB[i] + mb1_c, 0.f);
            *(u16*)(smem + M1_OFF + (lg * 4 + i) * 272 + c2) = (u16)cvtpk(mv, mv);
        }
        __syncthreads();

        // ================= PHASE 2: GRU1(t) + loss(t-1) =================
        const char* h0nr = h0n + lr * 272;
        bf16x8 ag0 = ldsAF(h0nr + lg * 16);
        bf16x8 ag1 = ldsAF(h0nr + 64 + lg * 16);
        bf16x8 ag2 = ldsAF(h0nr + 128 + lg * 16);
        bf16x8 ag3 = ldsAF(h0nr + 192 + lg * 16);
        bf16x8 av0 = ldsAF(h1r + lg * 16);
        bf16x8 av1 = ldsAF(h1r + 64 + lg * 16);
        bf16x8 av2 = ldsAF(h1r + 128 + lg * 16);
        bf16x8 av3 = ldsAF(h1r + 192 + lg * 16);
        f32x4 RA = mfma16(ag0, wW[1][0][0], zero);
        RA = mfma16(ag1, wW[1][0][1], RA);
        RA = mfma16(ag2, wW[1][0][2], RA);
        RA = mfma16(ag3, wW[1][0][3], RA);
        f32x4 RB = mfma16(av0, wW[2][0][0], zero);
        RB = mfma16(av1, wW[2][0][1], RB);
        RB = mfma16(av2, wW[2][0][2], RB);
        RB = mfma16(av3, wW[2][0][3], RB);
        f32x4 ZA = mfma16(ag0, wW[1][1][0], zero);
        ZA = mfma16(ag1, wW[1][1][1], ZA);
        ZA = mfma16(ag2, wW[1][1][2], ZA);
        ZA = mfma16(ag3, wW[1][1][3], ZA);
        f32x4 ZB = mfma16(av0, wW[2][1][0], zero);
        ZB = mfma16(av1, wW[2][1][1], ZB);
        ZB = mfma16(av2, wW[2][1][2], ZB);
        ZB = mfma16(av3, wW[2][1][3], ZB);
        f32x4 NI = mfma16(ag0, wW[1][2][0], zero);
        NI = mfma16(ag1, wW[1][2][1], NI);
        NI = mfma16(ag2, wW[1][2][2], NI);
        NI = mfma16(ag3, wW[1][2][3], NI);
        f32x4 NH = mfma16(av0, wW[2][2][0], zero);
        NH = mfma16(av1, wW[2][2][1], NH);
        NH = mfma16(av2, wW[2][2][2], NH);
        NH = mfma16(av3, wW[2][2][3], NH);
#pragma unroll
        for (int i = 0; i < 4; ++i) {
            float rr = sigm(RA[i] + RB[i]);
            float zz = sigm(ZA[i] + ZB[i]);
            float nn = tanh_fast(fmaf(rr, NH[i], NI[i]));
            float hnew = fmaf(zz, hp1[i] - nn, nn);
            hp1[i] = hnew;
            *(u16*)(h1n + (lg * 4 + i) * 272 + c2) = (u16)cvtpk(hnew, hnew);
        }
        if (w == 7) {  // y_hat(t-1) = m1(t-1) @ mE^T + mbE ; loss
            const char* m1r = smem + M1_OFF + lr * 272;
            bf16x8 q0 = ldsAF(m1r + lg * 16);
            bf16x8 q1 = ldsAF(m1r + 64 + lg * 16);
            bf16x8 q2 = ldsAF(m1r + 128 + lg * 16);
            bf16x8 q3 = ldsAF(m1r + 192 + lg * 16);
            f32x4 lA = mfma16(q0, ldsAF(smem + WL_OFF + 69 * 1024 + lane * 16), zero);
            lA = mfma16(q1, ldsAF(smem + WL_OFF + 70 * 1024 + lane * 16), lA);
            f32x4 lB = mfma16(q2, ldsAF(smem + WL_OFF + 71 * 1024 + lane * 16), zero);
            lB = mfma16(q3, ldsAF(smem + WL_OFF + 72 * 1024 + lane * 16), lB);
            const float gd = (t > 0) ? 1.f : 0.f;
#pragma unroll
            for (int i = 0; i < 4; ++i) {
                float yh = lA[i] + lB[i] + mbE_l;
                float yv = bf2f(*(const u16*)(smem + YCH_OFF + s * 768 + (lg * 4 + i) * 48 + lr * 2));
                float d = yh - yv;
                loss = fmaf(gd * d, d, loss);
            }
        }
        __syncthreads();
    }

    // ================= tail: m1(1023) + loss(1023) =================
    {
        const char* h0c = smem + H0_OFF;   // buffer 0 holds h0(1024)... == h0n(1023)
        const char* h1c = smem + H1_OFF;   // buffer 0 holds h1n(1023)
        const char* h1r = h1c + lr * 272;
        const char* h0r = h0c + lr * 272;
        // x(1023)
        bf16x8 ad0 = ldsAF((lg < 2) ? (smem + UCH_OFF + 31 * 768 + lr * 48 + lg * 16)
                                    : (h1r + (lg - 2) * 16));
        bf16x8 ad1 = ldsAF(h1r + 32 + lg * 16);
        bf16x8 ad2 = ldsAF(h1r + 96 + lg * 16);
        bf16x8 ad3 = ldsAF(h1r + 160 + lg * 16);
        bf16x8 ad4t = ldsAF(h1r + 224 + (lg & 1) * 16);
        bf16x8 ad4 = (lg < 2) ? ad4t : z8;
        f32x4 xa = mfma16(ldsAF(smem + WL_OFF + 24 * 1024 + lane * 16), ad0, zero);
        xa = mfma16(ldsAF(smem + WL_OFF + 25 * 1024 + lane * 16), ad1, xa);
        xa = mfma16(ldsAF(smem + WL_OFF + 26 * 1024 + lane * 16), ad2, xa);
        f32x4 xb = mfma16(ldsAF(smem + WL_OFF + 27 * 1024 + lane * 16), ad3, zero);
        xb = mfma16(ldsAF(smem + WL_OFF + 28 * 1024 + lane * 16), ad4, xb);
        uint32 pk0 = cvtpk(xa[0] + xb[0] + dbc4[0], xa[1] + xb[1] + dbc4[1]);
        uint32 pk1 = cvtpk(xa[2] + xb[2] + dbc4[2], xa[3] + xb[3] + dbc4[3]);
        uint32 d0 = (uint32)__builtin_amdgcn_ds_bpermute(bp0, (int)pk0);
        uint32 d1 = (uint32)__builtin_amdgcn_ds_bpermute(bp0, (int)pk1);
        uint32 d2 = (uint32)__builtin_amdgcn_ds_bpermute(bp0 + 64, (int)pk0);
        uint32 d3 = (uint32)__builtin_amdgcn_ds_bpermute(bp0 + 64, (int)pk1);
        bf16x8 xfrag = __builtin_bit_cast(bf16x8, (uint4){d0, d1, d2, d3});
        // m1(1023)
        bf16x8 t0 = ldsAF(h0r + (lg & 1) * 16);
        bf16x8 am0 = (lg < 2) ? xfrag : t0;
        bf16x8 am1 = ldsAF(h0r + 32 + lg * 16);
        bf16x8 am2 = ldsAF(h0r + 96 + lg * 16);
        bf16x8 am3 = ldsAF(h0r + 160 + lg * 16);
        bf16x8 am4t = ldsAF(h0r + 224 + (lg & 1) * 16);
        bf16x8 am4 = (lg < 2) ? am4t : z8;
        f32x4 mA = mfma16(am0, ldsAF(smem + WL_OFF + (29 + w * 5 + 0) * 1024 + lane * 16), zero);
        mA = mfma16(am1, ldsAF(smem + WL_OFF + (29 + w * 5 + 1) * 1024 + lane * 16), mA);
        mA = mfma16(am2, ldsAF(smem + WL_OFF + (29 + w * 5 + 2) * 1024 + lane * 16), mA);
        f32x4 mB = mfma16(am3, ldsAF(smem + WL_OFF + (29 + w * 5 + 3) * 1024 + lane * 16), zero);
        mB = mfma16(am4, ldsAF(smem + WL_OFF + (29 + w * 5 + 4) * 1024 + lane * 16), mB);
#pragma unroll
        for (int i = 0; i < 4; ++i) {
            float mv = fmaxf(mA[i] + mB[i] + mb1_c, 0.f);
            *(u16*)(smem + M1_OFF + (lg * 4 + i) * 272 + c2) = (u16)cvtpk(mv, mv);
        }
        __syncthreads();
        if (w == 7) {
            const char* m1r = smem + M1_OFF + lr * 272;
            bf16x8 q0 = ldsAF(m1r + lg * 16);
            bf16x8 q1 = ldsAF(m1r + 64 + lg * 16);
            bf16x8 q2 = ldsAF(m1r + 128 + lg * 16);
            bf16x8 q3 = ldsAF(m1r + 192 + lg * 16);
            f32x4 lA = mfma16(q0, ldsAF(smem + WL_OFF + 69 * 1024 + lane * 16), zero);
            lA = mfma16(q1, ldsAF(smem + WL_OFF + 70 * 1024 + lane * 16), lA);
            f32x4 lB = mfma16(q2, ldsAF(smem + WL_OFF + 71 * 1024 + lane * 16), zero);
            lB = mfma16(q3, ldsAF(smem + WL_OFF + 72 * 1024 + lane * 16), lB);
#pragma unroll
            for (int i = 0; i < 4; ++i) {
                float yh = lA[i] + lB[i] + mbE_l;
                float yv = yg[(r0 + lg * 4 + i) * 16384 + lr * 1024 + 1023];
                float d = yh - yv;
                loss = fmaf(d, d, loss);
            }
        }
    }

    if (w == 7) {
#pragma unroll
        for (int off = 32; off > 0; off >>= 1) loss += __shfl_down(loss, off, 64);
        if (lane == 0) atomicAdd(out, loss);
    }
}

extern "C" void kernel_launch(void* const* d_in, const int* in_sizes, int n_in,
                              void* d_out, int out_size, void* d_ws, size_t ws_size,
                              hipStream_t stream) {
    const float* u    = (const float*)d_in[0];
    const float* y    = (const float*)d_in[1];
    const float* h0   = (const float*)d_in[2];
    const float* Wih0 = (const float*)d_in[3];
    const float* Whh0 = (const float*)d_in[4];
    const float* Wih1 = (const float*)d_in[5];
    const float* Whh1 = (const float*)d_in[6];
    const float* dW1  = (const float*)d_in[7];
    const float* db1  = (const float*)d_in[8];
    const float* dW2  = (const float*)d_in[9];
    const float* db2  = (const float*)d_in[10];
    const float* mW1  = (const float*)d_in[11];
    const float* mb1  = (const float*)d_in[12];
    const float* mW2  = (const float*)d_in[13];
    const float* mb2  = (const float*)d_in[14];
    const float* mW3  = (const float*)d_in[15];
    const float* mb3  = (const float*)d_in[16];
    float* out = (float*)d_out;
    char* ws = (char*)d_ws;

    prep1<<<dim3(18), dim3(256), 0, stream>>>(dW1, db1, dW2, db2, mW2, mb2, mW3, mb3, ws, out);
    prep2<<<dim3(NT_TOT), dim3(64), 0, stream>>>(Wih0, Whh0, Wih1, Whh1, mW1, ws);
    rnn_main<<<dim3(16), dim3(512), 0, stream>>>(u, y, h0, ws, mb1,
                                                 (const float*)(ws + SC_DBC),
                                                 (const float*)(ws + SC_MBE), out);
}